// Round 3
// baseline (323.485 us; speedup 1.0000x reference)
//
#include <hip/hip_runtime.h>

#define B_    2048
#define K_    32
#define D_    768
#define DICT_ 24576
#define C_    64

#define ENTRY_CAP (1 << 20)   // 1M entries * 16B = 16 MiB
// ws layout: [0]=count (int), [256..] bdc float[DICT_], [256+4*DICT_ ..] entries int4[ENTRY_CAP]

// K1: bdc[r] = dot(up_encoder_w[r,:], b_dec). One wave per row. Also zeros count.
__global__ __launch_bounds__(256) void bdc_kernel(const float* __restrict__ up_enc,
                                                  const float* __restrict__ b_dec,
                                                  float* __restrict__ bdc,
                                                  int* __restrict__ count) {
    if (blockIdx.x == 0 && threadIdx.x == 0) *count = 0;
    int wave = threadIdx.x >> 6;
    int lane = threadIdx.x & 63;
    int row  = blockIdx.x * 4 + wave;
    const float4* rp = (const float4*)(up_enc + (size_t)row * D_);
    const float4* bp = (const float4*)b_dec;
    float acc = 0.f;
    #pragma unroll
    for (int i = 0; i < 3; ++i) {
        float4 a = rp[lane + 64 * i];
        float4 b = bp[lane + 64 * i];
        acc += a.x * b.x + a.y * b.y + a.z * b.z + a.w * b.w;
    }
    #pragma unroll
    for (int off = 32; off; off >>= 1) acc += __shfl_xor(acc, off);
    if (lane == 0) bdc[row] = acc;
}

// K2: one wave per item. Lane c holds conn[di][c]. For each j (scalar loads,
// no shfl chain): ballot-match, compact (item,tgt,w) entries. Writes bias to out.
__global__ __launch_bounds__(256) void match_kernel(const float* __restrict__ up_vals,
                                                    const int*   __restrict__ up_idx,
                                                    const int*   __restrict__ down_idx,
                                                    const int*   __restrict__ conn,
                                                    const float* __restrict__ bdc,
                                                    int*  __restrict__ count,
                                                    int4* __restrict__ entries,
                                                    float* __restrict__ out) {
    int wave = threadIdx.x >> 6;
    int lane = threadIdx.x & 63;
    int item = blockIdx.x * 4 + wave;
    int b    = __builtin_amdgcn_readfirstlane(item >> 5);

    int di = down_idx[item];
    int allowed = conn[(size_t)di * C_ + lane];
    bool valid  = allowed >= 0;

    const int*   ub = up_idx  + (size_t)b * K_;
    const float* vb = up_vals + (size_t)b * K_;

    #pragma unroll 1
    for (int j = 0; j < K_; ++j) {
        int tgt = __builtin_amdgcn_readfirstlane(ub[j]);   // wave-uniform, L1-hot
        unsigned long long m = __ballot(valid && (allowed == tgt));
        if (m != 0) {                                       // wave-uniform branch
            if (lane == 0) {
                float w = (float)__popcll(m) * vb[j];
                int idx = atomicAdd(count, 1);
                if (idx < ENTRY_CAP)
                    entries[idx] = make_int4(item, tgt, __float_as_int(w), 0);
            }
        }
    }
    if (lane == 0) out[item] = bdc[up_idx[item]];
}

// K3: grid-stride over compacted entries; one wave per entry.
//   out[item] += w * dot(down_enc[di], up_dec[:, tgt])
__global__ __launch_bounds__(256) void pairdot_kernel(const float* __restrict__ up_dec,
                                                      const float* __restrict__ down_enc,
                                                      const int*   __restrict__ down_idx,
                                                      const int*   __restrict__ count,
                                                      const int4*  __restrict__ entries,
                                                      float* __restrict__ out) {
    int lane   = threadIdx.x & 63;
    int gwave  = (blockIdx.x * blockDim.x + threadIdx.x) >> 6;
    int nwaves = (gridDim.x * blockDim.x) >> 6;
    int n = *count;
    if (n > ENTRY_CAP) n = ENTRY_CAP;

    for (int e = gwave; e < n; e += nwaves) {
        int4 ent = entries[e];
        int item = ent.x, tgt = ent.y;
        float w  = __int_as_float(ent.z);
        int di   = down_idx[item];
        const float* drow = down_enc + (size_t)di * D_;
        float p = 0.f;
        #pragma unroll
        for (int ii = 0; ii < 12; ++ii) {
            int d = lane + 64 * ii;
            p += drow[d] * up_dec[(size_t)d * DICT_ + tgt];
        }
        #pragma unroll
        for (int off = 32; off; off >>= 1) p += __shfl_xor(p, off);
        if (lane == 0) atomicAdd(&out[item], w * p);
    }
}

// Fallback (round-2 fused) if workspace is too small.
__global__ __launch_bounds__(256) void scae_fused_kernel(
        const float* __restrict__ up_vals, const float* __restrict__ up_dec,
        const float* __restrict__ down_enc, const float* __restrict__ up_enc,
        const float* __restrict__ b_dec, const int* __restrict__ up_idx,
        const int* __restrict__ down_idx, const int* __restrict__ conn,
        float* __restrict__ out) {
    int wave = threadIdx.x >> 6;
    int lane = threadIdx.x & 63;
    int item = blockIdx.x * 4 + wave;
    int b    = item >> 5;
    int ui = up_idx[item];
    const float4* rp = (const float4*)(up_enc + (size_t)ui * D_);
    const float4* bp = (const float4*)b_dec;
    float acc = 0.f;
    #pragma unroll
    for (int ii = 0; ii < 3; ++ii) {
        float4 a = rp[lane + 64 * ii]; float4 bb = bp[lane + 64 * ii];
        acc += a.x * bb.x + a.y * bb.y + a.z * bb.z + a.w * bb.w;
    }
    int di = down_idx[item];
    int allowed = conn[(size_t)di * C_ + lane];
    bool valid = allowed >= 0;
    int myup = up_idx[b * K_ + (lane & 31)];
    float myval = up_vals[b * K_ + (lane & 31)];
    const float* drow = down_enc + (size_t)di * D_;
    #pragma unroll 1
    for (int j = 0; j < K_; ++j) {
        int tgt = __shfl(myup, j);
        unsigned long long m = __ballot(valid && (allowed == tgt));
        if (m != 0) {
            float w = (float)__popcll(m) * __shfl(myval, j);
            float partial = 0.f;
            #pragma unroll
            for (int ii = 0; ii < 12; ++ii) {
                int d = lane + 64 * ii;
                partial += drow[d] * up_dec[(size_t)d * DICT_ + tgt];
            }
            acc += w * partial;
        }
    }
    #pragma unroll
    for (int off = 32; off; off >>= 1) acc += __shfl_xor(acc, off);
    if (lane == 0) out[item] = acc;
}

extern "C" void kernel_launch(void* const* d_in, const int* in_sizes, int n_in,
                              void* d_out, int out_size, void* d_ws, size_t ws_size,
                              hipStream_t stream) {
    (void)in_sizes; (void)n_in; (void)out_size;
    const float* up_vals  = (const float*)d_in[0];
    const float* up_dec   = (const float*)d_in[1];
    const float* down_enc = (const float*)d_in[2];
    const float* up_enc   = (const float*)d_in[3];
    const float* b_dec    = (const float*)d_in[4];
    const int*   up_idx   = (const int*)d_in[5];
    const int*   down_idx = (const int*)d_in[6];
    const int*   conn     = (const int*)d_in[7];
    float* out = (float*)d_out;

    size_t need = 256 + (size_t)DICT_ * 4 + (size_t)ENTRY_CAP * 16;
    if (ws_size < need) {
        scae_fused_kernel<<<(B_ * K_) / 4, 256, 0, stream>>>(
            up_vals, up_dec, down_enc, up_enc, b_dec, up_idx, down_idx, conn, out);
        return;
    }

    int*   count   = (int*)d_ws;
    float* bdc     = (float*)((char*)d_ws + 256);
    int4*  entries = (int4*)((char*)d_ws + 256 + (size_t)DICT_ * 4);

    bdc_kernel<<<DICT_ / 4, 256, 0, stream>>>(up_enc, b_dec, bdc, count);
    match_kernel<<<(B_ * K_) / 4, 256, 0, stream>>>(up_vals, up_idx, down_idx, conn,
                                                    bdc, count, entries, out);
    pairdot_kernel<<<1024, 256, 0, stream>>>(up_dec, down_enc, down_idx,
                                             count, entries, out);
}

// Round 4
// 303.349 us; speedup vs baseline: 1.0664x; 1.0664x over previous
//
#include <hip/hip_runtime.h>

#define B_    2048
#define K_    32
#define D_    768
#define DICT_ 24576
#define C_    64

#define NGRP  (DICT_ / 16)   // 1536 line-groups (16 columns per 64B line)
#define BCAP  16             // bucket capacity (lambda ~3.2, overflow ~never)
#define OCAP  8192           // overflow list capacity
#define OWAVES 256           // waves dedicated to overflow entries

struct Ent { unsigned pk; float w; };   // pk = item<<15 | tgt

// K1: bdc[r] = dot(up_encoder_w[r,:], b_dec); block 0 also zeros counters.
__global__ __launch_bounds__(256) void bdc_kernel(const float* __restrict__ up_enc,
                                                  const float* __restrict__ b_dec,
                                                  float* __restrict__ bdc,
                                                  int* __restrict__ grpCount,
                                                  int* __restrict__ overflowCount) {
    if (blockIdx.x == 0) {
        for (int i = threadIdx.x; i < NGRP; i += 256) grpCount[i] = 0;
        if (threadIdx.x == 0) *overflowCount = 0;
    }
    int wave = threadIdx.x >> 6;
    int lane = threadIdx.x & 63;
    int row  = blockIdx.x * 4 + wave;
    const float4* rp = (const float4*)(up_enc + (size_t)row * D_);
    const float4* bp = (const float4*)b_dec;
    float acc = 0.f;
    #pragma unroll
    for (int i = 0; i < 3; ++i) {
        float4 a = rp[lane + 64 * i];
        float4 b = bp[lane + 64 * i];
        acc += a.x * b.x + a.y * b.y + a.z * b.z + a.w * b.w;
    }
    #pragma unroll
    for (int off = 32; off; off >>= 1) acc += __shfl_xor(acc, off);
    if (lane == 0) bdc[row] = acc;
}

// K2: one wave per item. Ballot-match; push entries into per-group buckets
// (line-group = tgt>>4) so pairdot can reuse 64B lines. Writes bias to out.
__global__ __launch_bounds__(256) void match_kernel(const float* __restrict__ up_vals,
                                                    const int*   __restrict__ up_idx,
                                                    const int*   __restrict__ down_idx,
                                                    const int*   __restrict__ conn,
                                                    const float* __restrict__ bdc,
                                                    int* __restrict__ grpCount,
                                                    Ent* __restrict__ buckets,
                                                    int* __restrict__ overflowCount,
                                                    Ent* __restrict__ overflow,
                                                    float* __restrict__ out) {
    int wave = threadIdx.x >> 6;
    int lane = threadIdx.x & 63;
    int item = blockIdx.x * 4 + wave;
    int b    = __builtin_amdgcn_readfirstlane(item >> 5);

    int di = down_idx[item];
    int allowed = conn[(size_t)di * C_ + lane];
    bool valid  = allowed >= 0;

    const int*   ub = up_idx  + (size_t)b * K_;
    const float* vb = up_vals + (size_t)b * K_;

    #pragma unroll 1
    for (int j = 0; j < K_; ++j) {
        int tgt = __builtin_amdgcn_readfirstlane(ub[j]);   // wave-uniform, L1-hot
        unsigned long long m = __ballot(valid && (allowed == tgt));
        if (m != 0) {                                       // wave-uniform branch
            if (lane == 0) {
                Ent e;
                e.pk = ((unsigned)item << 15) | (unsigned)tgt;
                e.w  = (float)__popcll(m) * vb[j];
                int g = tgt >> 4;
                int idx = atomicAdd(&grpCount[g], 1);
                if (idx < BCAP) {
                    buckets[g * BCAP + idx] = e;
                } else {
                    int o = atomicAdd(overflowCount, 1);
                    if (o < OCAP) overflow[o] = e;
                }
            }
        }
    }
    if (lane == 0) out[item] = bdc[up_idx[item]];
}

// K3: one wave per group-bucket; entries in a bucket share up_dec 64B lines
// (same 16-column group) -> per-d loads after the first are L1 hits.
__global__ __launch_bounds__(256) void pairdot_kernel(const float* __restrict__ up_dec,
                                                      const float* __restrict__ down_enc,
                                                      const int*   __restrict__ down_idx,
                                                      const int*   __restrict__ grpCount,
                                                      const Ent*   __restrict__ buckets,
                                                      const int*   __restrict__ overflowCount,
                                                      const Ent*   __restrict__ overflow,
                                                      float* __restrict__ out) {
    int lane = threadIdx.x & 63;
    int gw   = (blockIdx.x * 256 + threadIdx.x) >> 6;

    if (gw < NGRP) {
        int g = gw;
        int n = grpCount[g];
        if (n > BCAP) n = BCAP;
        for (int base = 0; base < n; base += 4) {
            int   items[4], tgts[4];
            float ws[4];
            const float* drows[4];
            #pragma unroll
            for (int t = 0; t < 4; ++t) {
                int e = (base + t < n) ? (base + t) : base;   // dup first as dummy
                Ent en = buckets[g * BCAP + e];
                ws[t]    = (base + t < n) ? en.w : 0.f;
                items[t] = (int)(en.pk >> 15);
                tgts[t]  = (int)(en.pk & 32767u);
                drows[t] = down_enc + (size_t)down_idx[items[t]] * D_;
            }
            float p[4] = {0.f, 0.f, 0.f, 0.f};
            #pragma unroll
            for (int ii = 0; ii < 12; ++ii) {
                int d = lane + 64 * ii;
                const float* uc = up_dec + (size_t)d * DICT_;
                #pragma unroll
                for (int t = 0; t < 4; ++t)
                    p[t] += drows[t][d] * uc[tgts[t]];   // same 64B line across t
            }
            #pragma unroll
            for (int off = 32; off; off >>= 1) {
                #pragma unroll
                for (int t = 0; t < 4; ++t) p[t] += __shfl_xor(p[t], off);
            }
            if (lane == 0) {
                #pragma unroll
                for (int t = 0; t < 4; ++t)
                    if (base + t < n) atomicAdd(&out[items[t]], ws[t] * p[t]);
            }
        }
    } else {
        // overflow entries: one wave per entry, grid-stride (expected empty)
        int ow = gw - NGRP;
        int nover = *overflowCount;
        if (nover > OCAP) nover = OCAP;
        for (int e = ow; e < nover; e += OWAVES) {
            Ent en = overflow[e];
            int item = (int)(en.pk >> 15);
            int tgt  = (int)(en.pk & 32767u);
            const float* drow = down_enc + (size_t)down_idx[item] * D_;
            float p = 0.f;
            #pragma unroll
            for (int ii = 0; ii < 12; ++ii) {
                int d = lane + 64 * ii;
                p += drow[d] * up_dec[(size_t)d * DICT_ + tgt];
            }
            #pragma unroll
            for (int off = 32; off; off >>= 1) p += __shfl_xor(p, off);
            if (lane == 0) atomicAdd(&out[item], en.w * p);
        }
    }
}

// Fallback (round-2 fused) if workspace is too small.
__global__ __launch_bounds__(256) void scae_fused_kernel(
        const float* __restrict__ up_vals, const float* __restrict__ up_dec,
        const float* __restrict__ down_enc, const float* __restrict__ up_enc,
        const float* __restrict__ b_dec, const int* __restrict__ up_idx,
        const int* __restrict__ down_idx, const int* __restrict__ conn,
        float* __restrict__ out) {
    int wave = threadIdx.x >> 6;
    int lane = threadIdx.x & 63;
    int item = blockIdx.x * 4 + wave;
    int b    = item >> 5;
    int ui = up_idx[item];
    const float4* rp = (const float4*)(up_enc + (size_t)ui * D_);
    const float4* bp = (const float4*)b_dec;
    float acc = 0.f;
    #pragma unroll
    for (int ii = 0; ii < 3; ++ii) {
        float4 a = rp[lane + 64 * ii]; float4 bb = bp[lane + 64 * ii];
        acc += a.x * bb.x + a.y * bb.y + a.z * bb.z + a.w * bb.w;
    }
    int di = down_idx[item];
    int allowed = conn[(size_t)di * C_ + lane];
    bool valid = allowed >= 0;
    int myup = up_idx[b * K_ + (lane & 31)];
    float myval = up_vals[b * K_ + (lane & 31)];
    const float* drow = down_enc + (size_t)di * D_;
    #pragma unroll 1
    for (int j = 0; j < K_; ++j) {
        int tgt = __shfl(myup, j);
        unsigned long long m = __ballot(valid && (allowed == tgt));
        if (m != 0) {
            float w = (float)__popcll(m) * __shfl(myval, j);
            float partial = 0.f;
            #pragma unroll
            for (int ii = 0; ii < 12; ++ii) {
                int d = lane + 64 * ii;
                partial += drow[d] * up_dec[(size_t)d * DICT_ + tgt];
            }
            acc += w * partial;
        }
    }
    #pragma unroll
    for (int off = 32; off; off >>= 1) acc += __shfl_xor(acc, off);
    if (lane == 0) out[item] = acc;
}

extern "C" void kernel_launch(void* const* d_in, const int* in_sizes, int n_in,
                              void* d_out, int out_size, void* d_ws, size_t ws_size,
                              hipStream_t stream) {
    (void)in_sizes; (void)n_in; (void)out_size;
    const float* up_vals  = (const float*)d_in[0];
    const float* up_dec   = (const float*)d_in[1];
    const float* down_enc = (const float*)d_in[2];
    const float* up_enc   = (const float*)d_in[3];
    const float* b_dec    = (const float*)d_in[4];
    const int*   up_idx   = (const int*)d_in[5];
    const int*   down_idx = (const int*)d_in[6];
    const int*   conn     = (const int*)d_in[7];
    float* out = (float*)d_out;

    // ws layout (8B-aligned offsets)
    size_t off_oc   = 0;                                   // overflowCount
    size_t off_gc   = 256;                                 // grpCount[NGRP]
    size_t off_bdc  = off_gc + (size_t)NGRP * 4;           // bdc[DICT_]
    size_t off_bkt  = off_bdc + (size_t)DICT_ * 4;         // buckets[NGRP*BCAP]
    size_t off_ovf  = off_bkt + (size_t)NGRP * BCAP * 8;   // overflow[OCAP]
    size_t need     = off_ovf + (size_t)OCAP * 8;

    if (ws_size < need) {
        scae_fused_kernel<<<(B_ * K_) / 4, 256, 0, stream>>>(
            up_vals, up_dec, down_enc, up_enc, b_dec, up_idx, down_idx, conn, out);
        return;
    }

    int*   overflowCount = (int*)((char*)d_ws + off_oc);
    int*   grpCount      = (int*)((char*)d_ws + off_gc);
    float* bdc           = (float*)((char*)d_ws + off_bdc);
    Ent*   buckets       = (Ent*)((char*)d_ws + off_bkt);
    Ent*   overflow      = (Ent*)((char*)d_ws + off_ovf);

    bdc_kernel<<<DICT_ / 4, 256, 0, stream>>>(up_enc, b_dec, bdc,
                                              grpCount, overflowCount);
    match_kernel<<<(B_ * K_) / 4, 256, 0, stream>>>(up_vals, up_idx, down_idx, conn,
                                                    bdc, grpCount, buckets,
                                                    overflowCount, overflow, out);
    pairdot_kernel<<<(NGRP + OWAVES) / 4, 256, 0, stream>>>(up_dec, down_enc, down_idx,
                                                            grpCount, buckets,
                                                            overflowCount, overflow, out);
}

// Round 5
// 283.805 us; speedup vs baseline: 1.1398x; 1.0689x over previous
//
#include <hip/hip_runtime.h>

#define B_    2048
#define K_    32
#define D_    768
#define DICT_ 24576
#define C_    64

#define NGRP   (DICT_ / 16)  // 1536 line-groups (16 columns per 64B line)
#define BCAP   16            // bucket capacity (lambda ~3.2)
#define OCAP   8192          // overflow list capacity
#define OWAVES 256           // waves for overflow entries
#define NCHUNK 6             // d-chunks per group: 768/6 = 128 d's per wave
#define CHUNKD (D_ / NCHUNK) // 128

struct Ent { unsigned pk; float w; };   // pk = item<<15 | tgt

// K1: bdc[r] = dot(up_encoder_w[r,:], b_dec); block 0 also zeros counters.
__global__ __launch_bounds__(256) void bdc_kernel(const float* __restrict__ up_enc,
                                                  const float* __restrict__ b_dec,
                                                  float* __restrict__ bdc,
                                                  int* __restrict__ grpCount,
                                                  int* __restrict__ overflowCount) {
    if (blockIdx.x == 0) {
        for (int i = threadIdx.x; i < NGRP; i += 256) grpCount[i] = 0;
        if (threadIdx.x == 0) *overflowCount = 0;
    }
    int wave = threadIdx.x >> 6;
    int lane = threadIdx.x & 63;
    int row  = blockIdx.x * 4 + wave;
    const float4* rp = (const float4*)(up_enc + (size_t)row * D_);
    const float4* bp = (const float4*)b_dec;
    float acc = 0.f;
    #pragma unroll
    for (int i = 0; i < 3; ++i) {
        float4 a = rp[lane + 64 * i];
        float4 b = bp[lane + 64 * i];
        acc += a.x * b.x + a.y * b.y + a.z * b.z + a.w * b.w;
    }
    #pragma unroll
    for (int off = 32; off; off >>= 1) acc += __shfl_xor(acc, off);
    if (lane == 0) bdc[row] = acc;
}

// K2: one wave per item. Ballot-match; push entries into per-group buckets
// (line-group = tgt>>4). Writes bias to out.
__global__ __launch_bounds__(256) void match_kernel(const float* __restrict__ up_vals,
                                                    const int*   __restrict__ up_idx,
                                                    const int*   __restrict__ down_idx,
                                                    const int*   __restrict__ conn,
                                                    const float* __restrict__ bdc,
                                                    int* __restrict__ grpCount,
                                                    Ent* __restrict__ buckets,
                                                    int* __restrict__ overflowCount,
                                                    Ent* __restrict__ overflow,
                                                    float* __restrict__ out) {
    int wave = threadIdx.x >> 6;
    int lane = threadIdx.x & 63;
    int item = blockIdx.x * 4 + wave;
    int b    = __builtin_amdgcn_readfirstlane(item >> 5);

    int di = down_idx[item];
    int allowed = conn[(size_t)di * C_ + lane];
    bool valid  = allowed >= 0;

    const int*   ub = up_idx  + (size_t)b * K_;
    const float* vb = up_vals + (size_t)b * K_;

    #pragma unroll 1
    for (int j = 0; j < K_; ++j) {
        int tgt = __builtin_amdgcn_readfirstlane(ub[j]);   // wave-uniform, L1-hot
        unsigned long long m = __ballot(valid && (allowed == tgt));
        if (m != 0) {                                       // wave-uniform branch
            if (lane == 0) {
                Ent e;
                e.pk = ((unsigned)item << 15) | (unsigned)tgt;
                e.w  = (float)__popcll(m) * vb[j];
                int g = tgt >> 4;
                int idx = atomicAdd(&grpCount[g], 1);
                if (idx < BCAP) {
                    buckets[g * BCAP + idx] = e;
                } else {
                    int o = atomicAdd(overflowCount, 1);
                    if (o < OCAP) overflow[o] = e;
                }
            }
        }
    }
    if (lane == 0) out[item] = bdc[up_idx[item]];
}

// K3: one wave per (group, d-chunk). Entries in a bucket share up_dec 64B
// lines; chunking D across 6 waves restores occupancy / outstanding loads.
__global__ __launch_bounds__(256) void pairdot_kernel(const float* __restrict__ up_dec,
                                                      const float* __restrict__ down_enc,
                                                      const int*   __restrict__ down_idx,
                                                      const int*   __restrict__ grpCount,
                                                      const Ent*   __restrict__ buckets,
                                                      const int*   __restrict__ overflowCount,
                                                      const Ent*   __restrict__ overflow,
                                                      float* __restrict__ out) {
    int lane = threadIdx.x & 63;
    int gw   = (blockIdx.x * 256 + threadIdx.x) >> 6;

    if (gw < NGRP * NCHUNK) {
        int g  = gw / NCHUNK;              // chunks of a group are adjacent waves
        int ch = gw - g * NCHUNK;          //   -> bucket/down_idx lines L1-shared
        int n = grpCount[g];
        if (n > BCAP) n = BCAP;
        if (n == 0) return;
        int d0 = ch * CHUNKD;
        for (int base = 0; base < n; base += 4) {
            int   items[4], tgts[4];
            float ws[4];
            const float* drows[4];
            #pragma unroll
            for (int t = 0; t < 4; ++t) {
                int e = (base + t < n) ? (base + t) : base;   // dup first as dummy
                Ent en = buckets[g * BCAP + e];
                ws[t]    = (base + t < n) ? en.w : 0.f;
                items[t] = (int)(en.pk >> 15);
                tgts[t]  = (int)(en.pk & 32767u);
                drows[t] = down_enc + (size_t)down_idx[items[t]] * D_;
            }
            float p[4] = {0.f, 0.f, 0.f, 0.f};
            #pragma unroll
            for (int ii = 0; ii < CHUNKD / 64; ++ii) {
                int d = d0 + lane + 64 * ii;
                const float* uc = up_dec + (size_t)d * DICT_;
                #pragma unroll
                for (int t = 0; t < 4; ++t)
                    p[t] += drows[t][d] * uc[tgts[t]];   // same 64B line across t
            }
            #pragma unroll
            for (int off = 32; off; off >>= 1) {
                #pragma unroll
                for (int t = 0; t < 4; ++t) p[t] += __shfl_xor(p[t], off);
            }
            if (lane == 0) {
                #pragma unroll
                for (int t = 0; t < 4; ++t)
                    if (base + t < n) atomicAdd(&out[items[t]], ws[t] * p[t]);
            }
        }
    } else {
        // overflow entries: grid-stride, one wave per entry (expected empty)
        int ow = gw - NGRP * NCHUNK;
        int nover = *overflowCount;
        if (nover > OCAP) nover = OCAP;
        for (int e = ow; e < nover; e += OWAVES) {
            Ent en = overflow[e];
            int item = (int)(en.pk >> 15);
            int tgt  = (int)(en.pk & 32767u);
            const float* drow = down_enc + (size_t)down_idx[item] * D_;
            float p = 0.f;
            #pragma unroll
            for (int ii = 0; ii < 12; ++ii) {
                int d = lane + 64 * ii;
                p += drow[d] * up_dec[(size_t)d * DICT_ + tgt];
            }
            #pragma unroll
            for (int off = 32; off; off >>= 1) p += __shfl_xor(p, off);
            if (lane == 0) atomicAdd(&out[item], en.w * p);
        }
    }
}

// Fallback (round-2 fused) if workspace is too small.
__global__ __launch_bounds__(256) void scae_fused_kernel(
        const float* __restrict__ up_vals, const float* __restrict__ up_dec,
        const float* __restrict__ down_enc, const float* __restrict__ up_enc,
        const float* __restrict__ b_dec, const int* __restrict__ up_idx,
        const int* __restrict__ down_idx, const int* __restrict__ conn,
        float* __restrict__ out) {
    int wave = threadIdx.x >> 6;
    int lane = threadIdx.x & 63;
    int item = blockIdx.x * 4 + wave;
    int b    = item >> 5;
    int ui = up_idx[item];
    const float4* rp = (const float4*)(up_enc + (size_t)ui * D_);
    const float4* bp = (const float4*)b_dec;
    float acc = 0.f;
    #pragma unroll
    for (int ii = 0; ii < 3; ++ii) {
        float4 a = rp[lane + 64 * ii]; float4 bb = bp[lane + 64 * ii];
        acc += a.x * bb.x + a.y * bb.y + a.z * bb.z + a.w * bb.w;
    }
    int di = down_idx[item];
    int allowed = conn[(size_t)di * C_ + lane];
    bool valid = allowed >= 0;
    int myup = up_idx[b * K_ + (lane & 31)];
    float myval = up_vals[b * K_ + (lane & 31)];
    const float* drow = down_enc + (size_t)di * D_;
    #pragma unroll 1
    for (int j = 0; j < K_; ++j) {
        int tgt = __shfl(myup, j);
        unsigned long long m = __ballot(valid && (allowed == tgt));
        if (m != 0) {
            float w = (float)__popcll(m) * __shfl(myval, j);
            float partial = 0.f;
            #pragma unroll
            for (int ii = 0; ii < 12; ++ii) {
                int d = lane + 64 * ii;
                partial += drow[d] * up_dec[(size_t)d * DICT_ + tgt];
            }
            acc += w * partial;
        }
    }
    #pragma unroll
    for (int off = 32; off; off >>= 1) acc += __shfl_xor(acc, off);
    if (lane == 0) out[item] = acc;
}

extern "C" void kernel_launch(void* const* d_in, const int* in_sizes, int n_in,
                              void* d_out, int out_size, void* d_ws, size_t ws_size,
                              hipStream_t stream) {
    (void)in_sizes; (void)n_in; (void)out_size;
    const float* up_vals  = (const float*)d_in[0];
    const float* up_dec   = (const float*)d_in[1];
    const float* down_enc = (const float*)d_in[2];
    const float* up_enc   = (const float*)d_in[3];
    const float* b_dec    = (const float*)d_in[4];
    const int*   up_idx   = (const int*)d_in[5];
    const int*   down_idx = (const int*)d_in[6];
    const int*   conn     = (const int*)d_in[7];
    float* out = (float*)d_out;

    // ws layout (8B-aligned offsets)
    size_t off_oc   = 0;                                   // overflowCount
    size_t off_gc   = 256;                                 // grpCount[NGRP]
    size_t off_bdc  = off_gc + (size_t)NGRP * 4;           // bdc[DICT_]
    size_t off_bkt  = off_bdc + (size_t)DICT_ * 4;         // buckets[NGRP*BCAP]
    size_t off_ovf  = off_bkt + (size_t)NGRP * BCAP * 8;   // overflow[OCAP]
    size_t need     = off_ovf + (size_t)OCAP * 8;

    if (ws_size < need) {
        scae_fused_kernel<<<(B_ * K_) / 4, 256, 0, stream>>>(
            up_vals, up_dec, down_enc, up_enc, b_dec, up_idx, down_idx, conn, out);
        return;
    }

    int*   overflowCount = (int*)((char*)d_ws + off_oc);
    int*   grpCount      = (int*)((char*)d_ws + off_gc);
    float* bdc           = (float*)((char*)d_ws + off_bdc);
    Ent*   buckets       = (Ent*)((char*)d_ws + off_bkt);
    Ent*   overflow      = (Ent*)((char*)d_ws + off_ovf);

    bdc_kernel<<<DICT_ / 4, 256, 0, stream>>>(up_enc, b_dec, bdc,
                                              grpCount, overflowCount);
    match_kernel<<<(B_ * K_) / 4, 256, 0, stream>>>(up_vals, up_idx, down_idx, conn,
                                                    bdc, grpCount, buckets,
                                                    overflowCount, overflow, out);
    int nwaves = NGRP * NCHUNK + OWAVES;           // 9472 waves
    pairdot_kernel<<<nwaves / 4, 256, 0, stream>>>(up_dec, down_enc, down_idx,
                                                   grpCount, buckets,
                                                   overflowCount, overflow, out);
}

// Round 6
// 270.667 us; speedup vs baseline: 1.1951x; 1.0485x over previous
//
#include <hip/hip_runtime.h>

#define B_    2048
#define K_    32
#define D_    768
#define DICT_ 24576
#define C_    64

#define KMAX   3                  // slots per column (lambda ~0.2)
#define OCAP   8192               // overflow capacity
#define NDCH   16                 // d-chunks
#define DCH    (D_ / NDCH)        // 48 rows per chunk
#define NCOLB  (DICT_ / 256)      // 96 column-chunks
#define NSCAN  (NCOLB * NDCH)     // 1536 scan blocks
#define NOVFB  8                  // overflow tail blocks (32 waves)

struct Slot { float w; int item; };
struct OEnt { float w; int item; int tgt; int pad; };

// K1: bdc[r] = dot(up_encoder_w[r,:], b_dec). Also zeros colCount/overflowCount.
__global__ __launch_bounds__(256) void bdc_kernel(const float* __restrict__ up_enc,
                                                  const float* __restrict__ b_dec,
                                                  float* __restrict__ bdc,
                                                  int* __restrict__ colCount,
                                                  int* __restrict__ overflowCount) {
    if (blockIdx.x < NCOLB) colCount[blockIdx.x * 256 + threadIdx.x] = 0;
    if (blockIdx.x == 0 && threadIdx.x == 0) *overflowCount = 0;

    int wave = threadIdx.x >> 6;
    int lane = threadIdx.x & 63;
    int row  = blockIdx.x * 4 + wave;
    const float4* rp = (const float4*)(up_enc + (size_t)row * D_);
    const float4* bp = (const float4*)b_dec;
    float acc = 0.f;
    #pragma unroll
    for (int i = 0; i < 3; ++i) {
        float4 a = rp[lane + 64 * i];
        float4 b = bp[lane + 64 * i];
        acc += a.x * b.x + a.y * b.y + a.z * b.z + a.w * b.w;
    }
    #pragma unroll
    for (int off = 32; off; off >>= 1) acc += __shfl_xor(acc, off);
    if (lane == 0) bdc[row] = acc;
}

// K2: one wave per item. Ballot-match; insert (w,item) into the matched
// column's slot list (column-direct; scan threads own columns). Bias -> out.
__global__ __launch_bounds__(256) void match_kernel(const float* __restrict__ up_vals,
                                                    const int*   __restrict__ up_idx,
                                                    const int*   __restrict__ down_idx,
                                                    const int*   __restrict__ conn,
                                                    const float* __restrict__ bdc,
                                                    int*  __restrict__ colCount,
                                                    Slot* __restrict__ slots,
                                                    int*  __restrict__ overflowCount,
                                                    OEnt* __restrict__ overflow,
                                                    float* __restrict__ out) {
    int wave = threadIdx.x >> 6;
    int lane = threadIdx.x & 63;
    int item = blockIdx.x * 4 + wave;
    int b    = __builtin_amdgcn_readfirstlane(item >> 5);

    int di = down_idx[item];
    int allowed = conn[(size_t)di * C_ + lane];
    bool valid  = allowed >= 0;

    const int*   ub = up_idx  + (size_t)b * K_;
    const float* vb = up_vals + (size_t)b * K_;

    #pragma unroll 1
    for (int j = 0; j < K_; ++j) {
        int tgt = __builtin_amdgcn_readfirstlane(ub[j]);   // wave-uniform, L1-hot
        unsigned long long m = __ballot(valid && (allowed == tgt));
        if (m != 0) {                                       // wave-uniform branch
            if (lane == 0) {
                float w = (float)__popcll(m) * vb[j];
                int idx = atomicAdd(&colCount[tgt], 1);
                if (idx < KMAX) {
                    slots[tgt * KMAX + idx] = Slot{w, item};
                } else {
                    int o = atomicAdd(overflowCount, 1);
                    if (o < OCAP) overflow[o] = OEnt{w, item, tgt, 0};
                }
            }
        }
    }
    if (lane == 0) out[item] = bdc[up_idx[item]];
}

// K3: sequential scan of up_dec. Block = 256 consecutive columns x 48 rows.
// Thread owns one column; <=KMAX entries accumulate in registers against
// float4-prefetched down_enc row slices. Tail blocks drain overflow.
__global__ __launch_bounds__(256) void pairdot_kernel(const float* __restrict__ up_dec,
                                                      const float* __restrict__ down_enc,
                                                      const int*   __restrict__ down_idx,
                                                      const int*   __restrict__ colCount,
                                                      const Slot*  __restrict__ slots,
                                                      const int*   __restrict__ overflowCount,
                                                      const OEnt*  __restrict__ overflow,
                                                      float* __restrict__ out) {
    int blk = blockIdx.x;
    if (blk < NSCAN) {
        int colb = blk % NCOLB;            // spread col-chunks across XCDs
        int dch  = blk / NCOLB;
        int c    = colb * 256 + threadIdx.x;
        int d0   = dch * DCH;

        int k = colCount[c];               // coalesced
        if (k > KMAX) k = KMAX;

        float w[KMAX];
        int   item[KMAX];
        const float* dp[KMAX];
        float p[KMAX];
        #pragma unroll
        for (int j = 0; j < KMAX; ++j) {
            if (j < k) {
                Slot s  = slots[c * KMAX + j];
                w[j]    = s.w;
                item[j] = s.item;
                dp[j]   = down_enc + (size_t)down_idx[s.item] * D_ + d0;
            } else {
                w[j] = 0.f; item[j] = 0; dp[j] = down_enc + d0;  // hot dummy line
            }
            p[j] = 0.f;
        }

        const float* up = up_dec + (size_t)d0 * DICT_ + c;
        #pragma unroll 4
        for (int dd = 0; dd < DCH; dd += 4) {
            float4 dr0 = *(const float4*)(dp[0] + dd);
            float4 dr1 = *(const float4*)(dp[1] + dd);
            float4 dr2 = *(const float4*)(dp[2] + dd);
            float v0 = up[(size_t)(dd + 0) * DICT_];   // coalesced stream
            float v1 = up[(size_t)(dd + 1) * DICT_];
            float v2 = up[(size_t)(dd + 2) * DICT_];
            float v3 = up[(size_t)(dd + 3) * DICT_];
            p[0] += v0 * dr0.x + v1 * dr0.y + v2 * dr0.z + v3 * dr0.w;
            p[1] += v0 * dr1.x + v1 * dr1.y + v2 * dr1.z + v3 * dr1.w;
            p[2] += v0 * dr2.x + v1 * dr2.y + v2 * dr2.z + v3 * dr2.w;
        }

        #pragma unroll
        for (int j = 0; j < KMAX; ++j)
            if (j < k) atomicAdd(&out[item[j]], w[j] * p[j]);
    } else {
        // overflow entries (expected ~1): one wave per entry, grid-stride
        int lane = threadIdx.x & 63;
        int gw   = (blk - NSCAN) * 4 + (threadIdx.x >> 6);
        int nov  = *overflowCount;
        if (nov > OCAP) nov = OCAP;
        for (int e = gw; e < nov; e += NOVFB * 4) {
            OEnt en = overflow[e];
            const float* drow = down_enc + (size_t)down_idx[en.item] * D_;
            float pp = 0.f;
            #pragma unroll
            for (int ii = 0; ii < 12; ++ii) {
                int d = lane + 64 * ii;
                pp += drow[d] * up_dec[(size_t)d * DICT_ + en.tgt];
            }
            #pragma unroll
            for (int off = 32; off; off >>= 1) pp += __shfl_xor(pp, off);
            if (lane == 0) atomicAdd(&out[en.item], en.w * pp);
        }
    }
}

// Fallback (round-2 fused) if workspace is too small.
__global__ __launch_bounds__(256) void scae_fused_kernel(
        const float* __restrict__ up_vals, const float* __restrict__ up_dec,
        const float* __restrict__ down_enc, const float* __restrict__ up_enc,
        const float* __restrict__ b_dec, const int* __restrict__ up_idx,
        const int* __restrict__ down_idx, const int* __restrict__ conn,
        float* __restrict__ out) {
    int wave = threadIdx.x >> 6;
    int lane = threadIdx.x & 63;
    int item = blockIdx.x * 4 + wave;
    int b    = item >> 5;
    int ui = up_idx[item];
    const float4* rp = (const float4*)(up_enc + (size_t)ui * D_);
    const float4* bp = (const float4*)b_dec;
    float acc = 0.f;
    #pragma unroll
    for (int ii = 0; ii < 3; ++ii) {
        float4 a = rp[lane + 64 * ii]; float4 bb = bp[lane + 64 * ii];
        acc += a.x * bb.x + a.y * bb.y + a.z * bb.z + a.w * bb.w;
    }
    int di = down_idx[item];
    int allowed = conn[(size_t)di * C_ + lane];
    bool valid = allowed >= 0;
    int myup = up_idx[b * K_ + (lane & 31)];
    float myval = up_vals[b * K_ + (lane & 31)];
    const float* drow = down_enc + (size_t)di * D_;
    #pragma unroll 1
    for (int j = 0; j < K_; ++j) {
        int tgt = __shfl(myup, j);
        unsigned long long m = __ballot(valid && (allowed == tgt));
        if (m != 0) {
            float w = (float)__popcll(m) * __shfl(myval, j);
            float partial = 0.f;
            #pragma unroll
            for (int ii = 0; ii < 12; ++ii) {
                int d = lane + 64 * ii;
                partial += drow[d] * up_dec[(size_t)d * DICT_ + tgt];
            }
            acc += w * partial;
        }
    }
    #pragma unroll
    for (int off = 32; off; off >>= 1) acc += __shfl_xor(acc, off);
    if (lane == 0) out[item] = acc;
}

extern "C" void kernel_launch(void* const* d_in, const int* in_sizes, int n_in,
                              void* d_out, int out_size, void* d_ws, size_t ws_size,
                              hipStream_t stream) {
    (void)in_sizes; (void)n_in; (void)out_size;
    const float* up_vals  = (const float*)d_in[0];
    const float* up_dec   = (const float*)d_in[1];
    const float* down_enc = (const float*)d_in[2];
    const float* up_enc   = (const float*)d_in[3];
    const float* b_dec    = (const float*)d_in[4];
    const int*   up_idx   = (const int*)d_in[5];
    const int*   down_idx = (const int*)d_in[6];
    const int*   conn     = (const int*)d_in[7];
    float* out = (float*)d_out;

    // ws layout (16B-aligned offsets)
    size_t off_oc   = 0;                                     // overflowCount
    size_t off_cc   = 256;                                   // colCount[DICT]
    size_t off_bdc  = off_cc  + (size_t)DICT_ * 4;           // bdc[DICT]
    size_t off_slot = off_bdc + (size_t)DICT_ * 4;           // slots[DICT*KMAX]
    size_t off_ovf  = off_slot + (size_t)DICT_ * KMAX * 8;   // overflow[OCAP]
    size_t need     = off_ovf + (size_t)OCAP * 16;

    if (ws_size < need) {
        scae_fused_kernel<<<(B_ * K_) / 4, 256, 0, stream>>>(
            up_vals, up_dec, down_enc, up_enc, b_dec, up_idx, down_idx, conn, out);
        return;
    }

    int*   overflowCount = (int*)((char*)d_ws + off_oc);
    int*   colCount      = (int*)((char*)d_ws + off_cc);
    float* bdc           = (float*)((char*)d_ws + off_bdc);
    Slot*  slots         = (Slot*)((char*)d_ws + off_slot);
    OEnt*  overflow      = (OEnt*)((char*)d_ws + off_ovf);

    bdc_kernel<<<DICT_ / 4, 256, 0, stream>>>(up_enc, b_dec, bdc,
                                              colCount, overflowCount);
    match_kernel<<<(B_ * K_) / 4, 256, 0, stream>>>(up_vals, up_idx, down_idx, conn,
                                                    bdc, colCount, slots,
                                                    overflowCount, overflow, out);
    pairdot_kernel<<<NSCAN + NOVFB, 256, 0, stream>>>(up_dec, down_enc, down_idx,
                                                      colCount, slots,
                                                      overflowCount, overflow, out);
}